// Round 16
// baseline (273.975 us; speedup 1.0000x reference)
//
#include <hip/hip_runtime.h>
#include <stdint.h>

#define MDIM 8192
#define NDIM 4096
#define KDIM 4096
#define QBLK 128
#define KB 32   // KDIM / QBLK
#define NB 32   // NDIM / QBLK

#define BM 256
#define BN 128
#define BK 128

typedef __attribute__((ext_vector_type(4))) int int32x4;

#define GPTR(p) ((const __attribute__((address_space(1))) void*)(p))
#define LPTR(p) ((__attribute__((address_space(3))) void*)(p))

__device__ __forceinline__ int quant1(float v, float s) {
  float q = rintf(v / s);
  q = fminf(fmaxf(q, -127.f), 127.f);
  return (int)q;
}

// ---------------- activation quant: one wave per (row m, kb-pair) ------------
__global__ __launch_bounds__(256) void quant_x_kernel(
    const float* __restrict__ x, int8_t* __restrict__ xq, float* __restrict__ xsT) {
  const int lane = threadIdx.x & 63;
  const int W = blockIdx.x * 4 + (threadIdx.x >> 6);   // global wave id
  const int m = W >> 4;          // row
  const int p = W & 15;          // kb pair
  const int half = lane >> 5;    // 0/1 -> kb = 2p + half
  const int l31 = lane & 31;
  const size_t base = (size_t)m * KDIM + (size_t)p * 256 + half * 128 + l31 * 4;

  const float4 v = *reinterpret_cast<const float4*>(x + base);
  float amax = fmaxf(fmaxf(fabsf(v.x), fabsf(v.y)), fmaxf(fabsf(v.z), fabsf(v.w)));
#pragma unroll
  for (int off = 16; off; off >>= 1)
    amax = fmaxf(amax, __shfl_xor(amax, off));
  const float scale = fmaxf(amax / 127.0f, 1e-12f);

  const int qa = quant1(v.x, scale);
  const int qb = quant1(v.y, scale);
  const int qc = quant1(v.z, scale);
  const int qd = quant1(v.w, scale);
  const uint32_t packed = (uint32_t)(qa & 0xff) | ((uint32_t)(qb & 0xff) << 8) |
                          ((uint32_t)(qc & 0xff) << 16) | ((uint32_t)(qd & 0xff) << 24);
  *reinterpret_cast<uint32_t*>(xq + base) = packed;
  if (l31 == 0) xsT[(size_t)(p * 2 + half) * MDIM + m] = scale;
}

// ---------------- weight quant: one 256-thread block per 128x128 block --------
__global__ __launch_bounds__(256) void quant_w_kernel(
    const float* __restrict__ w, int8_t* __restrict__ wq, float* __restrict__ ws) {
  const int nb = blockIdx.x >> 5;   // / KB
  const int kb = blockIdx.x & 31;   // % KB
  const int tid = threadIdx.x;
  const int lane = tid & 63;
  const int wv = tid >> 6;
  __shared__ float red[4];

  float amax = 0.f;
  float4 vals[16];
#pragma unroll
  for (int i = 0; i < 16; ++i) {
    const int idx4 = tid + i * 256;         // 4096 float4 per block
    const int row = idx4 >> 5;
    const int c4 = idx4 & 31;
    const float4 v = *reinterpret_cast<const float4*>(
        w + (size_t)(nb * QBLK + row) * KDIM + (size_t)kb * QBLK + c4 * 4);
    vals[i] = v;
    amax = fmaxf(amax, fmaxf(fmaxf(fabsf(v.x), fabsf(v.y)),
                             fmaxf(fabsf(v.z), fabsf(v.w))));
  }
#pragma unroll
  for (int off = 32; off; off >>= 1)
    amax = fmaxf(amax, __shfl_xor(amax, off));
  if (lane == 0) red[wv] = amax;
  __syncthreads();
  amax = fmaxf(fmaxf(red[0], red[1]), fmaxf(red[2], red[3]));
  const float scale = fmaxf(amax / 127.0f, 1e-12f);

#pragma unroll
  for (int i = 0; i < 16; ++i) {
    const int idx4 = tid + i * 256;
    const int row = idx4 >> 5;
    const int c4 = idx4 & 31;
    const float4 v = vals[i];
    const int qa = quant1(v.x, scale);
    const int qb = quant1(v.y, scale);
    const int qc = quant1(v.z, scale);
    const int qd = quant1(v.w, scale);
    const uint32_t packed = (uint32_t)(qa & 0xff) | ((uint32_t)(qb & 0xff) << 8) |
                            ((uint32_t)(qc & 0xff) << 16) | ((uint32_t)(qd & 0xff) << 24);
    *reinterpret_cast<uint32_t*>(
        wq + (size_t)(nb * QBLK + row) * KDIM + (size_t)kb * QBLK + c4 * 4) = packed;
  }
  if (tid == 0) ws[nb * KB + kb] = scale;
}

// ---------------- int8 blockwise GEMM: 256x128 tile, 8 waves -----------------
// Same verified structure as the 220us 128^2 kernel (single-buffer stage ->
// sync -> compute -> sync; multi-block overlap does the pipelining), but with
// 2x the M-extent per block: staged DMA per output -25%, barriers per output
// halved, LDS 48 KB (still 2 blocks/CU), BN=128=QBLK keeps sw block-uniform.
// Swizzle identical (rows are 128 B): chunk c in 0..7, phys = c ^ (row&7);
// linear LDS dest + inverse-swizzled global source. Per-wave inner loop and
// epilogue identical to the verified 4x4-fragment code (wave tile 64x64).
__global__ __launch_bounds__(512) void gemm_i8_kernel(
    const int8_t* __restrict__ Aq, const int8_t* __restrict__ Bq,
    const float* __restrict__ xsT, const float* __restrict__ wsp,
    const float* __restrict__ bias, float* __restrict__ C) {
  __shared__ int8_t As[BM * BK];      // 32 KB, swizzled
  __shared__ int8_t Bs[BN * BK];      // 16 KB, swizzled

  const int tid = threadIdx.x;
  const int lane = tid & 63;
  const int wid = tid >> 6;     // 0..7
  const int wm = wid >> 1;      // wave row 0..3 (64 rows each)
  const int wn = wid & 1;       // wave col 0..1 (64 cols each)
  const int l15 = lane & 15;
  const int lhi = lane >> 4;

  const int tiles_n = NDIM / BN;          // 32
  const int bm = blockIdx.x / tiles_n;    // 0..31
  const int bn = blockIdx.x % tiles_n;    // 0..31
  const int brow = bm * BM;
  const int bcol = bn * BN;

  float accf[4][4][4];
#pragma unroll
  for (int m = 0; m < 4; ++m)
#pragma unroll
    for (int n = 0; n < 4; ++n)
#pragma unroll
      for (int r = 0; r < 4; ++r) accf[m][n][r] = 0.f;

  const int32x4 zeroc = {0, 0, 0, 0};

  const int8_t* arow = Aq + (size_t)brow * KDIM;
  const int8_t* brp = Bq + (size_t)bcol * KDIM;

  for (int kb = 0; kb < KB; ++kb) {
    const int k0 = kb * BK;
    // stage A tile (256x128 = 32 KB): 2048 chunks, 4 issues x 512 threads
#pragma unroll
    for (int i = 0; i < 4; ++i) {
      const int idx = i * 512 + tid;
      const int r = idx >> 3;
      const int c = idx & 7;
      const int csrc = c ^ (r & 7);
      __builtin_amdgcn_global_load_lds(GPTR(arow + (size_t)r * KDIM + k0 + csrc * 16),
                                       LPTR(As + idx * 16), 16, 0, 0);
    }
    // stage B tile (128x128 = 16 KB): 1024 chunks, 2 issues x 512 threads
#pragma unroll
    for (int i = 0; i < 2; ++i) {
      const int idx = i * 512 + tid;
      const int r = idx >> 3;
      const int c = idx & 7;
      const int csrc = c ^ (r & 7);
      __builtin_amdgcn_global_load_lds(GPTR(brp + (size_t)r * KDIM + k0 + csrc * 16),
                                       LPTR(Bs + idx * 16), 16, 0, 0);
    }
    __syncthreads();

    // issue the scale loads early; L2-resident, covered by the MFMA phase
    float4 sx4[4];
#pragma unroll
    for (int m = 0; m < 4; ++m)
      sx4[m] = *reinterpret_cast<const float4*>(
          xsT + (size_t)kb * MDIM + brow + wm * 64 + m * 16 + lhi * 4);
    const float sw = wsp[bn * KB + kb];   // block-uniform (BN == QBLK)

    int32x4 acci[4][4];
    {
      const int cl = lhi;                      // kk=0 chunk
      int32x4 af[4], bf[4];
#pragma unroll
      for (int m = 0; m < 4; ++m) {
        const int rowA = wm * 64 + m * 16 + l15;
        af[m] = *reinterpret_cast<const int32x4*>(
            As + rowA * 128 + ((cl ^ (rowA & 7)) * 16));
      }
#pragma unroll
      for (int n = 0; n < 4; ++n) {
        const int rowB = wn * 64 + n * 16 + l15;
        bf[n] = *reinterpret_cast<const int32x4*>(
            Bs + rowB * 128 + ((cl ^ (rowB & 7)) * 16));
      }
#pragma unroll
      for (int m = 0; m < 4; ++m)
#pragma unroll
        for (int n = 0; n < 4; ++n)
          acci[m][n] = __builtin_amdgcn_mfma_i32_16x16x64_i8(af[m], bf[n], zeroc, 0, 0, 0);
    }
    {
      const int cl = 4 + lhi;                  // kk=1 chunk
      int32x4 af[4], bf[4];
#pragma unroll
      for (int m = 0; m < 4; ++m) {
        const int rowA = wm * 64 + m * 16 + l15;
        af[m] = *reinterpret_cast<const int32x4*>(
            As + rowA * 128 + ((cl ^ (rowA & 7)) * 16));
      }
#pragma unroll
      for (int n = 0; n < 4; ++n) {
        const int rowB = wn * 64 + n * 16 + l15;
        bf[n] = *reinterpret_cast<const int32x4*>(
            Bs + rowB * 128 + ((cl ^ (rowB & 7)) * 16));
      }
#pragma unroll
      for (int m = 0; m < 4; ++m)
#pragma unroll
        for (int n = 0; n < 4; ++n)
          acci[m][n] = __builtin_amdgcn_mfma_i32_16x16x64_i8(af[m], bf[n], acci[m][n], 0, 0, 0);
    }

#pragma unroll
    for (int m = 0; m < 4; ++m) {
#pragma unroll
      for (int r = 0; r < 4; ++r) {
        const float sx = ((const float*)&sx4[m])[r] * sw;
#pragma unroll
        for (int n = 0; n < 4; ++n)
          accf[m][n][r] += (float)acci[m][n][r] * sx;
      }
    }
    __syncthreads();
  }

  // epilogue: bias + store f32
#pragma unroll
  for (int m = 0; m < 4; ++m) {
#pragma unroll
    for (int r = 0; r < 4; ++r) {
      const int row = brow + wm * 64 + m * 16 + lhi * 4 + r;
#pragma unroll
      for (int n = 0; n < 4; ++n) {
        const int col = bcol + wn * 64 + n * 16 + l15;
        C[(size_t)row * NDIM + col] = accf[m][n][r] + bias[col];
      }
    }
  }
}

extern "C" void kernel_launch(void* const* d_in, const int* in_sizes, int n_in,
                              void* d_out, int out_size, void* d_ws, size_t ws_size,
                              hipStream_t stream) {
  const float* x = (const float*)d_in[0];
  const float* w = (const float*)d_in[1];
  const float* bias = (const float*)d_in[2];
  float* out = (float*)d_out;

  char* base = (char*)d_ws;
  size_t off = 0;
  int8_t* xq = (int8_t*)(base + off); off += (size_t)MDIM * KDIM;          // 32 MB
  int8_t* wq = (int8_t*)(base + off); off += (size_t)NDIM * KDIM;          // 16 MB
  float* xsT = (float*)(base + off); off += (size_t)KB * MDIM * 4;         // 1 MB
  float* wsc = (float*)(base + off);                                       // 4 KB

  quant_x_kernel<<<(MDIM * 16) / 4, 256, 0, stream>>>(x, xq, xsT);
  quant_w_kernel<<<NB * KB, 256, 0, stream>>>(w, wq, wsc);
  gemm_i8_kernel<<<(MDIM / BM) * (NDIM / BN), 512, 0, stream>>>(xq, wq, xsT, wsc, bias, out);
}

// Round 17
// 261.289 us; speedup vs baseline: 1.0486x; 1.0486x over previous
//
#include <hip/hip_runtime.h>
#include <stdint.h>

#define MDIM 8192
#define NDIM 4096
#define KDIM 4096
#define QBLK 128
#define KB 32   // KDIM / QBLK
#define NB 32   // NDIM / QBLK

#define BM 128
#define BN 128
#define BK 128

typedef __attribute__((ext_vector_type(4))) int int32x4;

#define GPTR(p) ((const __attribute__((address_space(1))) void*)(p))
#define LPTR(p) ((__attribute__((address_space(3))) void*)(p))

__device__ __forceinline__ int quant1(float v, float s) {
  float q = rintf(v / s);
  q = fminf(fmaxf(q, -127.f), 127.f);
  return (int)q;
}

// ---------------- activation quant: one wave per (row m, kb-pair) ------------
// lanes 0-31 cover quant block 2p, lanes 32-63 cover block 2p+1; float4/lane;
// amax reduce via shfl_xor within each 32-lane group.
__global__ __launch_bounds__(256) void quant_x_kernel(
    const float* __restrict__ x, int8_t* __restrict__ xq, float* __restrict__ xsT) {
  const int lane = threadIdx.x & 63;
  const int W = blockIdx.x * 4 + (threadIdx.x >> 6);   // global wave id
  const int m = W >> 4;          // row
  const int p = W & 15;          // kb pair
  const int half = lane >> 5;    // 0/1 -> kb = 2p + half
  const int l31 = lane & 31;
  const size_t base = (size_t)m * KDIM + (size_t)p * 256 + half * 128 + l31 * 4;

  const float4 v = *reinterpret_cast<const float4*>(x + base);
  float amax = fmaxf(fmaxf(fabsf(v.x), fabsf(v.y)), fmaxf(fabsf(v.z), fabsf(v.w)));
#pragma unroll
  for (int off = 16; off; off >>= 1)
    amax = fmaxf(amax, __shfl_xor(amax, off));
  const float scale = fmaxf(amax / 127.0f, 1e-12f);

  const int qa = quant1(v.x, scale);
  const int qb = quant1(v.y, scale);
  const int qc = quant1(v.z, scale);
  const int qd = quant1(v.w, scale);
  const uint32_t packed = (uint32_t)(qa & 0xff) | ((uint32_t)(qb & 0xff) << 8) |
                          ((uint32_t)(qc & 0xff) << 16) | ((uint32_t)(qd & 0xff) << 24);
  *reinterpret_cast<uint32_t*>(xq + base) = packed;
  if (l31 == 0) xsT[(size_t)(p * 2 + half) * MDIM + m] = scale;
}

// ---------------- weight quant: one 256-thread block per 128x128 block --------
__global__ __launch_bounds__(256) void quant_w_kernel(
    const float* __restrict__ w, int8_t* __restrict__ wq, float* __restrict__ ws) {
  const int nb = blockIdx.x >> 5;   // / KB
  const int kb = blockIdx.x & 31;   // % KB
  const int tid = threadIdx.x;
  const int lane = tid & 63;
  const int wv = tid >> 6;
  __shared__ float red[4];

  float amax = 0.f;
  float4 vals[16];
#pragma unroll
  for (int i = 0; i < 16; ++i) {
    const int idx4 = tid + i * 256;         // 4096 float4 per block
    const int row = idx4 >> 5;
    const int c4 = idx4 & 31;
    const float4 v = *reinterpret_cast<const float4*>(
        w + (size_t)(nb * QBLK + row) * KDIM + (size_t)kb * QBLK + c4 * 4);
    vals[i] = v;
    amax = fmaxf(amax, fmaxf(fmaxf(fabsf(v.x), fabsf(v.y)),
                             fmaxf(fabsf(v.z), fabsf(v.w))));
  }
#pragma unroll
  for (int off = 32; off; off >>= 1)
    amax = fmaxf(amax, __shfl_xor(amax, off));
  if (lane == 0) red[wv] = amax;
  __syncthreads();
  amax = fmaxf(fmaxf(red[0], red[1]), fmaxf(red[2], red[3]));
  const float scale = fmaxf(amax / 127.0f, 1e-12f);

#pragma unroll
  for (int i = 0; i < 16; ++i) {
    const int idx4 = tid + i * 256;
    const int row = idx4 >> 5;
    const int c4 = idx4 & 31;
    const float4 v = vals[i];
    const int qa = quant1(v.x, scale);
    const int qb = quant1(v.y, scale);
    const int qc = quant1(v.z, scale);
    const int qd = quant1(v.w, scale);
    const uint32_t packed = (uint32_t)(qa & 0xff) | ((uint32_t)(qb & 0xff) << 8) |
                            ((uint32_t)(qc & 0xff) << 16) | ((uint32_t)(qd & 0xff) << 24);
    *reinterpret_cast<uint32_t*>(
        wq + (size_t)(nb * QBLK + row) * KDIM + (size_t)kb * QBLK + c4 * 4) = packed;
  }
  if (tid == 0) ws[nb * KB + kb] = scale;
}

// ---------------- int8 blockwise GEMM (best measured: 220 us) ----------------
// LDS A/B tiles XOR-swizzled on 16B chunks: linear LDS dest + inverse-swizzled
// global source (global_load_lds writes linearly), swizzled ds_read address.
// MFMA i32_16x16x64_i8; kk=0 uses zeroc as C-in; scales read per-kb from
// L2-warm xsT as float4. Pipelining comes from 2-3 resident blocks/CU
// overlapping (m97 mechanism). Measured optimum of this design family:
// schedule variants (R4,R5,R9,R11,R13), occupancy variants (R7,R8,R9),
// addressing (R6), tile size (R7) and tile aspect (R15) all slower.
__global__ __launch_bounds__(256) void gemm_i8_kernel(
    const int8_t* __restrict__ Aq, const int8_t* __restrict__ Bq,
    const float* __restrict__ xsT, const float* __restrict__ wsp,
    const float* __restrict__ bias, float* __restrict__ C) {
  __shared__ int8_t As[BM * BK];      // 16 KB, swizzled
  __shared__ int8_t Bs[BN * BK];      // 16 KB, swizzled

  const int tid = threadIdx.x;
  const int lane = tid & 63;
  const int wv = tid >> 6;
  const int wr = wv >> 1;       // wave row 0..1
  const int wc = wv & 1;        // wave col 0..1
  const int l15 = lane & 15;
  const int lhi = lane >> 4;

  const int tiles_n = NDIM / BN;          // 32
  const int bm = blockIdx.x / tiles_n;
  const int bn = blockIdx.x % tiles_n;
  const int brow = bm * BM;
  const int bcol = bn * BN;

  float accf[4][4][4];
#pragma unroll
  for (int m = 0; m < 4; ++m)
#pragma unroll
    for (int n = 0; n < 4; ++n)
#pragma unroll
      for (int r = 0; r < 4; ++r) accf[m][n][r] = 0.f;

  const int32x4 zeroc = {0, 0, 0, 0};

  const int8_t* arow = Aq + (size_t)brow * KDIM;
  const int8_t* brp = Bq + (size_t)bcol * KDIM;

  for (int kb = 0; kb < KB; ++kb) {
    const int k0 = kb * BK;
#pragma unroll
    for (int i = 0; i < 4; ++i) {
      const int off = (i * 256 + tid) * 16;
      const int r = off >> 7;
      const int c = (off >> 4) & 7;
      const int csrc = c ^ (r & 7);
      __builtin_amdgcn_global_load_lds(GPTR(arow + (size_t)r * KDIM + k0 + csrc * 16),
                                       LPTR(As + off), 16, 0, 0);
    }
#pragma unroll
    for (int i = 0; i < 4; ++i) {
      const int off = (i * 256 + tid) * 16;
      const int r = off >> 7;
      const int c = (off >> 4) & 7;
      const int csrc = c ^ (r & 7);
      __builtin_amdgcn_global_load_lds(GPTR(brp + (size_t)r * KDIM + k0 + csrc * 16),
                                       LPTR(Bs + off), 16, 0, 0);
    }
    __syncthreads();

    // issue the scale loads early; L2-resident, covered by the MFMA phase
    float4 sx4[4];
#pragma unroll
    for (int m = 0; m < 4; ++m)
      sx4[m] = *reinterpret_cast<const float4*>(
          xsT + (size_t)kb * MDIM + brow + wr * 64 + m * 16 + lhi * 4);
    const float sw = wsp[bn * KB + kb];   // wave-uniform

    int32x4 acci[4][4];
    {
      const int cl = lhi;                      // kk=0 chunk
      int32x4 af[4], bf[4];
#pragma unroll
      for (int m = 0; m < 4; ++m) {
        const int rowA = wr * 64 + m * 16 + l15;
        af[m] = *reinterpret_cast<const int32x4*>(
            As + rowA * 128 + ((cl ^ (rowA & 7)) * 16));
      }
#pragma unroll
      for (int n = 0; n < 4; ++n) {
        const int rowB = wc * 64 + n * 16 + l15;
        bf[n] = *reinterpret_cast<const int32x4*>(
            Bs + rowB * 128 + ((cl ^ (rowB & 7)) * 16));
      }
#pragma unroll
      for (int m = 0; m < 4; ++m)
#pragma unroll
        for (int n = 0; n < 4; ++n)
          acci[m][n] = __builtin_amdgcn_mfma_i32_16x16x64_i8(af[m], bf[n], zeroc, 0, 0, 0);
    }
    {
      const int cl = 4 + lhi;                  // kk=1 chunk
      int32x4 af[4], bf[4];
#pragma unroll
      for (int m = 0; m < 4; ++m) {
        const int rowA = wr * 64 + m * 16 + l15;
        af[m] = *reinterpret_cast<const int32x4*>(
            As + rowA * 128 + ((cl ^ (rowA & 7)) * 16));
      }
#pragma unroll
      for (int n = 0; n < 4; ++n) {
        const int rowB = wc * 64 + n * 16 + l15;
        bf[n] = *reinterpret_cast<const int32x4*>(
            Bs + rowB * 128 + ((cl ^ (rowB & 7)) * 16));
      }
#pragma unroll
      for (int m = 0; m < 4; ++m)
#pragma unroll
        for (int n = 0; n < 4; ++n)
          acci[m][n] = __builtin_amdgcn_mfma_i32_16x16x64_i8(af[m], bf[n], acci[m][n], 0, 0, 0);
    }

#pragma unroll
    for (int m = 0; m < 4; ++m) {
#pragma unroll
      for (int r = 0; r < 4; ++r) {
        const float sx = ((const float*)&sx4[m])[r] * sw;
#pragma unroll
        for (int n = 0; n < 4; ++n)
          accf[m][n][r] += (float)acci[m][n][r] * sx;
      }
    }
    __syncthreads();
  }

  // epilogue: bias + store f32
#pragma unroll
  for (int m = 0; m < 4; ++m) {
#pragma unroll
    for (int r = 0; r < 4; ++r) {
      const int row = brow + wr * 64 + m * 16 + lhi * 4 + r;
#pragma unroll
      for (int n = 0; n < 4; ++n) {
        const int col = bcol + wc * 64 + n * 16 + l15;
        C[(size_t)row * NDIM + col] = accf[m][n][r] + bias[col];
      }
    }
  }
}

extern "C" void kernel_launch(void* const* d_in, const int* in_sizes, int n_in,
                              void* d_out, int out_size, void* d_ws, size_t ws_size,
                              hipStream_t stream) {
  const float* x = (const float*)d_in[0];
  const float* w = (const float*)d_in[1];
  const float* bias = (const float*)d_in[2];
  float* out = (float*)d_out;

  char* base = (char*)d_ws;
  size_t off = 0;
  int8_t* xq = (int8_t*)(base + off); off += (size_t)MDIM * KDIM;          // 32 MB
  int8_t* wq = (int8_t*)(base + off); off += (size_t)NDIM * KDIM;          // 16 MB
  float* xsT = (float*)(base + off); off += (size_t)KB * MDIM * 4;         // 1 MB
  float* wsc = (float*)(base + off);                                       // 4 KB

  quant_x_kernel<<<(MDIM * 16) / 4, 256, 0, stream>>>(x, xq, xsT);
  quant_w_kernel<<<NB * KB, 256, 0, stream>>>(w, wq, wsc);
  gemm_i8_kernel<<<(MDIM / BM) * (NDIM / BN), 256, 0, stream>>>(xq, wq, xsT, wsc, bias, out);
}